// Round 6
// baseline (379.206 us; speedup 1.0000x reference)
//
#include <hip/hip_runtime.h>

#define D 128
#define NN 100000
#define PB 391          // coarse buckets: dst >> 8
#define EPB 4096        // edges per partition block
#define PREP_BLKS 12756 // 12500 cvt + 256 wt

typedef __attribute__((ext_vector_type(8))) short short8;
typedef __attribute__((ext_vector_type(16))) float floatx16;
typedef __attribute__((ext_vector_type(2))) float floatx2;

__device__ inline unsigned short bf16_rne(float f) {
    unsigned int u = __float_as_uint(f);
    u += 0x7fff + ((u >> 16) & 1);
    return (unsigned short)(u >> 16);
}
__device__ inline unsigned char fp8_enc1(float f) {
    return (unsigned char)(__builtin_amdgcn_cvt_pk_fp8_f32(f, f, 0, false) & 0xff);
}

// ---------------------------------------------------------------------------
// F-layout (MFMA A-fragment order) for a [N][128] bf16 matrix, N%32==0:
//   F(n,d) = (n>>5)*4096 + ((d>>3)*32 + (n&31))*8 + (d&7)      [elements]
// A-fragment load for 32x32x16 MFMA (lane=hf*32+r, k=kc*16+hf*8+j) is then
//   tile_base + kc*512 + lane*8  -> linear 1KB coalesced wave load.
//
// RACE LESSON (round 5): within ONE kernel, any write region must be disjoint
// from every read region (block order undefined). Layer-1 fusion violated
// this (out overlaps h18 in d_out) -> NaN. Layer 0 fused is disjoint-safe;
// layer 1 runs as two dispatches.
// ---------------------------------------------------------------------------

// Fused prep+count: [0,12500) cvt feat->bf16(F-layout)+fp8 | [12500,12756)
// build Wt in B-fragment order | [12756, 12756+nblk) coarse edge count.
__global__ __launch_bounds__(256) void prep_count_kernel(
    const float* __restrict__ feat, unsigned short* __restrict__ feat16,
    unsigned char* __restrict__ feat8,
    const float* __restrict__ Ws0, const float* __restrict__ Wn0,
    const float* __restrict__ Ws1, const float* __restrict__ Wn1,
    unsigned short* __restrict__ wt0, unsigned short* __restrict__ wt1,
    const int* __restrict__ dst, unsigned int* __restrict__ bucketCnt,
    unsigned int* __restrict__ blockBase, int E)
{
    __shared__ unsigned int h[PB];
    int bid = blockIdx.x;
    if (bid < 12500) {
        int i = bid * 256 + threadIdx.x;                 // float4 index
        float4 v = *(const float4*)(feat + (size_t)i * 4);
        unsigned short u[4] = { bf16_rne(v.x), bf16_rne(v.y), bf16_rne(v.z), bf16_rne(v.w) };
        int n  = i >> 5;              // row
        int d0 = (i & 31) * 4;        // col (multiple of 4, within an 8-group)
        size_t f = (size_t)(n >> 5) * 4096 + (size_t)((d0 >> 3) * 32 + (n & 31)) * 8 + (d0 & 7);
        *(uint2*)(feat16 + f) = *(uint2*)u;
        int w = __builtin_amdgcn_cvt_pk_fp8_f32(v.x, v.y, 0, false);
        w = __builtin_amdgcn_cvt_pk_fp8_f32(v.z, v.w, w, true);
        ((unsigned int*)feat8)[i] = (unsigned int)w;     // fp8 stays row-major
    } else if (bid < PREP_BLKS) {
        int i = (bid - 12500) * 256 + threadIdx.x;       // 0..65535
        int layer = i >> 15;
        int r = i & 32767;
        int n = r >> 8;
        int k = r & 255;
        const float* Ws = layer ? Ws1 : Ws0;
        const float* Wn = layer ? Wn1 : Wn0;
        float v = (k < 128) ? Ws[(size_t)k * 128 + n] : Wn[(size_t)(k - 128) * 128 + n];
        unsigned short* wt = layer ? wt1 : wt0;
        // B-fragment order
        int ct = n >> 5, nn = n & 31;
        int hs = k >> 7, k7 = k & 127;
        int kc = k7 >> 4, hf = (k7 >> 3) & 1, j = k7 & 7;
        int frag = ((((ct * 2 + hs) * 8 + kc) * 2 + hf) * 32 + nn) * 8 + j;
        wt[frag] = bf16_rne(v);
    } else {
        const int b = bid - PREP_BLKS;
        const int t = threadIdx.x;
        for (int i = t; i < PB; i += 256) h[i] = 0;
        __syncthreads();
        const int base = b * EPB;
#pragma unroll
        for (int k = 0; k < EPB / 256; k++) {
            int e = base + k * 256 + t;
            if (e < E) atomicAdd(&h[(unsigned)dst[e] >> 8], 1u);
        }
        __syncthreads();
        for (int i = t; i < PB; i += 256) {
            unsigned int c = h[i];
            unsigned int o = 0;
            if (c) o = atomicAdd(&bucketCnt[i], c);
            blockBase[(size_t)b * PB + i] = o;
        }
    }
}

// single block: exclusive scan of PB bucket counts -> bucketStart[PB+1]
__global__ __launch_bounds__(512) void part_scan_kernel(
    const unsigned int* __restrict__ bucketCnt, unsigned int* __restrict__ bucketStart,
    int E)
{
    __shared__ unsigned int sd[512];
    int t = threadIdx.x;
    unsigned int v = (t < PB) ? bucketCnt[t] : 0u;
    sd[t] = v; __syncthreads();
    for (int off = 1; off < 512; off <<= 1) {
        unsigned int x = (t >= off) ? sd[t - off] : 0u;
        __syncthreads();
        sd[t] += x;
        __syncthreads();
    }
    if (t < PB) bucketStart[t] = sd[t] - v;
    if (t == 0) bucketStart[PB] = (unsigned int)E;
}

// P2: scatter packed (src<<8 | dst&255) into bucket regions; ranks via LDS.
__global__ __launch_bounds__(256) void part_scatter_kernel(
    const int* __restrict__ src, const int* __restrict__ dst,
    const unsigned int* __restrict__ bucketStart,
    const unsigned int* __restrict__ blockBase,
    unsigned int* __restrict__ pairs, int E)
{
    __shared__ unsigned int h[PB];
    const int t = threadIdx.x;
    const int b = blockIdx.x;
    for (int i = t; i < PB; i += 256) h[i] = 0;
    __syncthreads();
    const int base = b * EPB;
#pragma unroll
    for (int k = 0; k < EPB / 256; k++) {
        int e = base + k * 256 + t;
        if (e < E) {
            unsigned int d = (unsigned int)dst[e];
            unsigned int bk = d >> 8;
            unsigned int lr = atomicAdd(&h[bk], 1u);
            unsigned int pos = bucketStart[bk] + blockBase[(size_t)b * PB + bk] + lr;
            pairs[pos] = ((unsigned int)src[e] << 8) | (d & 255u);
        }
    }
}

// P3: per-bucket fine CSR (256 dsts): LDS hist + scan -> row_ptr, cursor -> col.
__global__ __launch_bounds__(256) void part_fine_kernel(
    const unsigned int* __restrict__ pairs, const unsigned int* __restrict__ bucketStart,
    int* __restrict__ row_ptr, int* __restrict__ col, int N, int E)
{
    __shared__ unsigned int h[256], sc[256], pos[256];
    const int t = threadIdx.x;
    const int b = blockIdx.x;
    h[t] = 0;
    __syncthreads();
    const unsigned int ebeg = bucketStart[b];
    const unsigned int eend = bucketStart[b + 1];
    for (unsigned int i = ebeg + t; i < eend; i += 256)
        atomicAdd(&h[pairs[i] & 255u], 1u);
    __syncthreads();
    sc[t] = h[t]; __syncthreads();
    for (int off = 1; off < 256; off <<= 1) {
        unsigned int x = (t >= off) ? sc[t - off] : 0u;
        __syncthreads();
        sc[t] += x;
        __syncthreads();
    }
    unsigned int excl = sc[t] - h[t];
    int node = b * 256 + t;
    if (node < N) row_ptr[node] = (int)(ebeg + excl);
    pos[t] = ebeg + excl;
    if (b == 0 && t == 0) row_ptr[N] = E;
    __syncthreads();
    for (unsigned int i = ebeg + t; i < eend; i += 256) {
        unsigned int p = pairs[i];
        unsigned int w = atomicAdd(&pos[p & 255u], 1u);
        col[w] = (int)(p >> 8);
    }
}

// ---------------------------------------------------------------------------
// FUSED SAGE layer 0: gather(mean of fp8 rows) -> LDS msg tile -> dual-GEMM
// 32x32x16_bf16 -> LN+ReLU -> h116 (F-layout) + h18 (row-major fp8).
// Region-safe: reads {feat16,CSR ws; feat8 d_out[25.6M,38.4M)}, writes
// {h116 ws; h18 d_out[38.4M,51.2M)} — all disjoint.
// LDS msg swizzle: ci=(lr>>5)*512+ln16*32+(lr&31); sl=ci^((ci>>5)&7) —
// write quads spread over 8 chunk-residues (2-way), fragment reads 2-way.
// C/D: col=lane&31, row=(reg&3)+8*(reg>>2)+4*(lane>>5).
// ---------------------------------------------------------------------------
__global__ __launch_bounds__(256, 3) void sage_layer_kernel(
    const unsigned short* __restrict__ A16,   // F-layout [N][128]
    const unsigned char*  __restrict__ H8,    // row-major fp8 [N][128]
    const int* __restrict__ row_ptr, const int* __restrict__ col,
    const int* __restrict__ in_deg,
    const unsigned short* __restrict__ Wt,    // B-fragment order, 32768 bf16
    const float* __restrict__ bias,
    const float* __restrict__ ln_g, const float* __restrict__ ln_b,
    unsigned short* __restrict__ Out16, unsigned char* __restrict__ Out8,
    int N)
{
    __shared__ char smem[49152];  // [0,32K): msg tile / sO16; [32K,48K): sO8

    const int tid  = threadIdx.x;
    const int wave = tid >> 6;
    const int lane = tid & 63;
    const int half = lane >> 5;
    const int n32  = lane & 31;
    const int quad = lane >> 4;
    const int ln16 = lane & 15;
    const int nq   = wave * 4 + quad;        // 0..15
    const int brow0 = blockIdx.x * 128;

    // ---- Phase 1: gather 8 nodes per 16-lane group into LDS msg tile ----
    {
        const size_t lo = (size_t)ln16 * 8;  // byte offset within 128B fp8 row
#pragma unroll 1
        for (int rep = 0; rep < 8; rep++) {
            int lr = rep * 16 + nq;          // 0..127
            int node = brow0 + lr;
            if (node < N) {
                int beg = row_ptr[node];
                int end = row_ptr[node + 1];
                float f[8] = {0.f,0.f,0.f,0.f,0.f,0.f,0.f,0.f};
                int j = beg;
                for (; j + 4 <= end; j += 4) {
                    int c0 = col[j], c1 = col[j + 1], c2 = col[j + 2], c3 = col[j + 3];
                    uint2 u0 = *(const uint2*)(H8 + (size_t)c0 * D + lo);
                    uint2 u1 = *(const uint2*)(H8 + (size_t)c1 * D + lo);
                    uint2 u2 = *(const uint2*)(H8 + (size_t)c2 * D + lo);
                    uint2 u3 = *(const uint2*)(H8 + (size_t)c3 * D + lo);
#pragma unroll
                    for (int q = 0; q < 4; q++) {
                        uint2 u = q == 0 ? u0 : q == 1 ? u1 : q == 2 ? u2 : u3;
                        floatx2 p0 = __builtin_amdgcn_cvt_pk_f32_fp8((int)u.x, false);
                        floatx2 p1 = __builtin_amdgcn_cvt_pk_f32_fp8((int)u.x, true);
                        floatx2 p2 = __builtin_amdgcn_cvt_pk_f32_fp8((int)u.y, false);
                        floatx2 p3 = __builtin_amdgcn_cvt_pk_f32_fp8((int)u.y, true);
                        f[0] += p0.x; f[1] += p0.y; f[2] += p1.x; f[3] += p1.y;
                        f[4] += p2.x; f[5] += p2.y; f[6] += p3.x; f[7] += p3.y;
                    }
                }
                for (; j < end; ++j) {
                    uint2 u = *(const uint2*)(H8 + (size_t)col[j] * D + lo);
                    floatx2 p0 = __builtin_amdgcn_cvt_pk_f32_fp8((int)u.x, false);
                    floatx2 p1 = __builtin_amdgcn_cvt_pk_f32_fp8((int)u.x, true);
                    floatx2 p2 = __builtin_amdgcn_cvt_pk_f32_fp8((int)u.y, false);
                    floatx2 p3 = __builtin_amdgcn_cvt_pk_f32_fp8((int)u.y, true);
                    f[0] += p0.x; f[1] += p0.y; f[2] += p1.x; f[3] += p1.y;
                    f[4] += p2.x; f[5] += p2.y; f[6] += p3.x; f[7] += p3.y;
                }
                int dg = in_deg[node];
                float invd = 1.f / (float)(dg > 1 ? dg : 1);
                unsigned short us[8];
#pragma unroll
                for (int i = 0; i < 8; i++) us[i] = bf16_rne(f[i] * invd);
                int ci = ((lr >> 5) << 9) + (ln16 << 5) + (lr & 31);
                int sl = ci ^ ((ci >> 5) & 7);
                *(uint4*)(smem + sl * 16) = *(const uint4*)us;
            }
        }
    }
    __syncthreads();   // msg tile complete

    // ---- Phase 2: dual GEMM ----
    const int NT = N >> 5;
    int tile = (brow0 >> 5) + wave;
    if (tile >= NT) tile = NT - 1;           // clamp; stores guarded below
    const short8* Af = (const short8*)(A16 + (size_t)tile * 4096);

    floatx16 acc[4];
#pragma unroll
    for (int ct = 0; ct < 4; ct++)
#pragma unroll
        for (int r = 0; r < 16; r++) acc[ct][r] = 0.f;

    // hs = 0: self features from global F-layout (linear 1KB wave loads)
#pragma unroll
    for (int kc = 0; kc < 8; kc++) {
        short8 a = Af[kc * 64 + lane];
#pragma unroll
        for (int ct = 0; ct < 4; ct++) {
            short8 b = *(const short8*)(Wt + ((size_t)((ct * 2 + 0) * 8 + kc) * 64 + lane) * 8);
            acc[ct] = __builtin_amdgcn_mfma_f32_32x32x16_bf16(a, b, acc[ct], 0, 0, 0);
        }
    }
    // hs = 1: msg from LDS (swizzled reads)
#pragma unroll
    for (int kc = 0; kc < 8; kc++) {
        int ci = (wave << 9) + (kc << 6) + lane;
        int sl = ci ^ ((ci >> 5) & 7);
        short8 a = *(const short8*)(smem + sl * 16);
#pragma unroll
        for (int ct = 0; ct < 4; ct++) {
            short8 b = *(const short8*)(Wt + ((size_t)((ct * 2 + 1) * 8 + kc) * 64 + lane) * 8);
            acc[ct] = __builtin_amdgcn_mfma_f32_32x32x16_bf16(a, b, acc[ct], 0, 0, 0);
        }
    }

    // ---- Epilogue: bias + LN + ReLU -> bf16(F) + fp8(row-major) ----
    float bb[4], gg[4], be[4];
#pragma unroll
    for (int ct = 0; ct < 4; ct++) {
        bb[ct] = bias[ct * 32 + n32];
        gg[ct] = ln_g[ct * 32 + n32];
        be[ct] = ln_b[ct * 32 + n32];
    }
    float v[4][16];
#pragma unroll
    for (int ct = 0; ct < 4; ct++)
#pragma unroll
        for (int r = 0; r < 16; r++) v[ct][r] = acc[ct][r] + bb[ct];

    float s[16], s2[16];
#pragma unroll
    for (int r = 0; r < 16; r++) {
        s[r]  = v[0][r] + v[1][r] + v[2][r] + v[3][r];
        s2[r] = v[0][r]*v[0][r] + v[1][r]*v[1][r] + v[2][r]*v[2][r] + v[3][r]*v[3][r];
    }
#pragma unroll
    for (int off = 1; off < 32; off <<= 1) {
#pragma unroll
        for (int r = 0; r < 16; r++) {
            s[r]  += __shfl_xor(s[r],  off);
            s2[r] += __shfl_xor(s2[r], off);
        }
    }
    __syncthreads();   // all waves done reading msg tile; reuse as sO16
    unsigned char* sO8 = (unsigned char*)smem + 32768;       // [128][128] byte
#pragma unroll
    for (int r = 0; r < 16; r++) {
        float mean = s[r] * (1.f / 128.f);
        float var  = s2[r] * (1.f / 128.f) - mean * mean;
        float rstd = rsqrtf(var + 1e-5f);
        int brow = wave * 32 + (r & 3) + 8 * (r >> 2) + 4 * half;
#pragma unroll
        for (int ct = 0; ct < 4; ct++) {
            float t = (v[ct][r] - mean) * rstd * gg[ct] + be[ct];
            t = t > 0.f ? t : 0.f;
            // sO16 in F-order with XOR slot swizzle (conflict-free 2B writes)
            int slot = (ct * 4 + (n32 >> 3)) ^ (brow & 15);
            *(unsigned short*)(smem + brow * 256 + slot * 16 + (n32 & 7) * 2) = bf16_rne(t);
            sO8[brow * 128 + ct * 32 + n32] = fp8_enc1(t);
        }
    }
    __syncthreads();
    // h116 (F-layout): linear global writes; LDS reads de-swizzled (<=4-way)
#pragma unroll
    for (int i = 0; i < 8; i++) {                 // 2048 uint4 chunks
        int ch = tid + i * 256;
        int tl = ch >> 9, p = ch & 511, kc2 = p >> 5, rr = p & 31;
        if (brow0 + tl * 32 + rr < N)
            *(uint4*)(Out16 + (size_t)brow0 * D + ch * 8) =
                *(const uint4*)&smem[(tl * 32 + rr) * 256 + ((kc2 ^ (rr & 15)) * 16)];
    }
#pragma unroll
    for (int i = 0; i < 4; i++) {                 // fp8: 1024 uint4 chunks
        int ch = tid + i * 256;
        if (brow0 + (ch >> 3) < N)
            *(uint4*)(Out8 + (size_t)brow0 * D + ch * 16) = *(const uint4*)&sO8[ch * 16];
    }
}

// ---------------------------------------------------------------------------
// Layer-1 gather: same gather math, but output staged through LDS so the
// F-layout global store is LINEAR (32KB contiguous per 128-node block) —
// fixes round 4's 512B-strided 16B scatter.
// ---------------------------------------------------------------------------
__global__ __launch_bounds__(256) void gather8f_kernel(
    const unsigned char* __restrict__ h8, const int* __restrict__ row_ptr,
    const int* __restrict__ col, const int* __restrict__ in_deg,
    unsigned short* __restrict__ msg16, int N)   // msg16: F-layout base
{
    __shared__ char smem[32768];
    const int tid  = threadIdx.x;
    const int nq   = tid >> 4;        // 0..15
    const int ln16 = tid & 15;
    const int brow0 = blockIdx.x * 128;
    const size_t lo = (size_t)ln16 * 8;

#pragma unroll 1
    for (int rep = 0; rep < 8; rep++) {
        int lr = rep * 16 + nq;
        int node = brow0 + lr;
        if (node < N) {
            int beg = row_ptr[node];
            int end = row_ptr[node + 1];
            float f[8] = {0.f,0.f,0.f,0.f,0.f,0.f,0.f,0.f};
            int j = beg;
            for (; j + 4 <= end; j += 4) {
                int c0 = col[j], c1 = col[j + 1], c2 = col[j + 2], c3 = col[j + 3];
                uint2 u0 = *(const uint2*)(h8 + (size_t)c0 * D + lo);
                uint2 u1 = *(const uint2*)(h8 + (size_t)c1 * D + lo);
                uint2 u2 = *(const uint2*)(h8 + (size_t)c2 * D + lo);
                uint2 u3 = *(const uint2*)(h8 + (size_t)c3 * D + lo);
#pragma unroll
                for (int q = 0; q < 4; q++) {
                    uint2 u = q == 0 ? u0 : q == 1 ? u1 : q == 2 ? u2 : u3;
                    floatx2 p0 = __builtin_amdgcn_cvt_pk_f32_fp8((int)u.x, false);
                    floatx2 p1 = __builtin_amdgcn_cvt_pk_f32_fp8((int)u.x, true);
                    floatx2 p2 = __builtin_amdgcn_cvt_pk_f32_fp8((int)u.y, false);
                    floatx2 p3 = __builtin_amdgcn_cvt_pk_f32_fp8((int)u.y, true);
                    f[0] += p0.x; f[1] += p0.y; f[2] += p1.x; f[3] += p1.y;
                    f[4] += p2.x; f[5] += p2.y; f[6] += p3.x; f[7] += p3.y;
                }
            }
            for (; j < end; ++j) {
                uint2 u = *(const uint2*)(h8 + (size_t)col[j] * D + lo);
                floatx2 p0 = __builtin_amdgcn_cvt_pk_f32_fp8((int)u.x, false);
                floatx2 p1 = __builtin_amdgcn_cvt_pk_f32_fp8((int)u.x, true);
                floatx2 p2 = __builtin_amdgcn_cvt_pk_f32_fp8((int)u.y, false);
                floatx2 p3 = __builtin_amdgcn_cvt_pk_f32_fp8((int)u.y, true);
                f[0] += p0.x; f[1] += p0.y; f[2] += p1.x; f[3] += p1.y;
                f[4] += p2.x; f[5] += p2.y; f[6] += p3.x; f[7] += p3.y;
            }
            int dg = in_deg[node];
            float invd = 1.f / (float)(dg > 1 ? dg : 1);
            unsigned short us[8];
#pragma unroll
            for (int i = 0; i < 8; i++) us[i] = bf16_rne(f[i] * invd);
            int ci = ((lr >> 5) << 9) + (ln16 << 5) + (lr & 31);
            int sl = ci ^ ((ci >> 5) & 7);
            *(uint4*)(smem + sl * 16) = *(const uint4*)us;
        }
    }
    __syncthreads();
    // linear copy-out: global chunk ch <- LDS slot ch^((ch>>5)&7)
#pragma unroll
    for (int i = 0; i < 8; i++) {
        int ch = tid + i * 256;                       // 0..2047
        int row = brow0 + ((ch >> 9) << 5) + (ch & 31);
        if (row < N) {
            int sl = ch ^ ((ch >> 5) & 7);
            *(uint4*)(msg16 + (size_t)brow0 * D + ch * 8) = *(const uint4*)(smem + sl * 16);
        }
    }
}

// ---------------------------------------------------------------------------
// Layer-1 GEMM (round-4 verified): barrier-free K-loop, F-layout A/Msg from
// global (linear 1KB wave loads), B fragment table (L2-hot); direct fp32
// full-line stores. No LDS.
// ---------------------------------------------------------------------------
__global__ __launch_bounds__(256, 3) void mfma32_kernel(
    const unsigned short* __restrict__ A16, const unsigned short* __restrict__ Msg16,
    const unsigned short* __restrict__ Wt,
    const float* __restrict__ bias,
    float* __restrict__ Out32, int N)
{
    const int tid  = threadIdx.x;
    const int wave = tid >> 6;
    const int lane = tid & 63;
    const int half = lane >> 5;
    const int n32  = lane & 31;
    const int brow0 = blockIdx.x * 128;
    const int wrow0 = brow0 + wave * 32;

    const int NT = N >> 5;
    int tile = wrow0 >> 5;
    if (tile >= NT) tile = NT - 1;
    const short8* Af = (const short8*)(A16   + (size_t)tile * 4096);
    const short8* Mf = (const short8*)(Msg16 + (size_t)tile * 4096);

    floatx16 acc[4];
#pragma unroll
    for (int ct = 0; ct < 4; ct++)
#pragma unroll
        for (int r = 0; r < 16; r++) acc[ct][r] = 0.f;

#pragma unroll
    for (int hs = 0; hs < 2; hs++) {
        const short8* Sf = hs ? Mf : Af;
#pragma unroll
        for (int kc = 0; kc < 8; kc++) {
            short8 a = Sf[kc * 64 + lane];
#pragma unroll
            for (int ct = 0; ct < 4; ct++) {
                short8 b = *(const short8*)(Wt + ((size_t)((ct * 2 + hs) * 8 + kc) * 64 + lane) * 8);
                acc[ct] = __builtin_amdgcn_mfma_f32_32x32x16_bf16(a, b, acc[ct], 0, 0, 0);
            }
        }
    }

    float bb[4];
#pragma unroll
    for (int ct = 0; ct < 4; ct++) bb[ct] = bias[ct * 32 + n32];

#pragma unroll
    for (int r = 0; r < 16; r++) {
        int row = wrow0 + (r & 3) + 8 * (r >> 2) + 4 * half;
        if (row < N) {
#pragma unroll
            for (int ct = 0; ct < 4; ct++)
                Out32[(size_t)row * D + ct * 32 + n32] = acc[ct][r] + bb[ct];
        }
    }
}

// ---------------------------------------------------------------------------
extern "C" void kernel_launch(void* const* d_in, const int* in_sizes, int n_in,
                              void* d_out, int out_size, void* d_ws, size_t ws_size,
                              hipStream_t stream)
{
    const float* feat = (const float*)d_in[0];
    const float* Ws0  = (const float*)d_in[1];
    const float* Wn0  = (const float*)d_in[2];
    const float* b0   = (const float*)d_in[3];
    const float* Ws1  = (const float*)d_in[4];
    const float* Wn1  = (const float*)d_in[5];
    const float* b1   = (const float*)d_in[6];
    const float* lng  = (const float*)d_in[7];
    const float* lnb  = (const float*)d_in[8];
    const int* esrc   = (const int*)d_in[9];
    const int* edst   = (const int*)d_in[10];
    const int* indeg  = (const int*)d_in[11];

    const int N = NN;
    const int E = in_sizes[9];

    float* out = (float*)d_out;

    // ws: feat16 | col | row_ptr | wt0 | wt1 | regD
    //   regD overlay (CSR build): bucketCnt | bucketStart | blockBase | pairs
    //   regD overlay (compute):   h1_16
    // d_out overlay (dead until final dispatch):
    //   [25.6M, 38.4M): feat8 | [38.4M, 51.2M): h18
    // Dispatch-level safety: L0 fused reads {feat16,feat8,CSR} writes
    // {h116,h18} (disjoint); gather8f reads h18 writes msg1F(=feat16 region,
    // dead); mfma32 reads {h116,msg1F} writes out (h18 dead by then).
    const int nblk = (E + EPB - 1) / EPB;
    char* ws = (char*)d_ws;
    size_t o = 0;
    auto alloc = [&](size_t bytes) { char* p = ws + o; o += (bytes + 15) & ~(size_t)15; return p; };
    unsigned short* feat16 = (unsigned short*)alloc((size_t)N * D * 2);
    int* col     = (int*)alloc((size_t)E * 4);
    int* row_ptr = (int*)alloc((size_t)(N + 1) * 4);
    unsigned short* wt0 = (unsigned short*)alloc(128 * 256 * 2);
    unsigned short* wt1 = (unsigned short*)alloc(128 * 256 * 2);
    size_t csr_bytes = (size_t)(512 + 512 + (size_t)nblk * PB + E) * 4 + 64;
    char* regD = alloc((size_t)N * D * 2 > csr_bytes ? (size_t)N * D * 2 : csr_bytes);
    unsigned int* bucketCnt   = (unsigned int*)regD;                  // 512 slots
    unsigned int* bucketStart = bucketCnt + 512;                      // 512 slots
    unsigned int* blockBase   = bucketStart + 512;                    // nblk*PB
    unsigned int* pairs       = blockBase + (size_t)nblk * PB;        // E
    unsigned short* h116 = (unsigned short*)regD;

    unsigned char*  feat8 = (unsigned char*)d_out + (size_t)N * D * 2;
    unsigned char*  h18   = (unsigned char*)d_out + (size_t)N * D * 3;
    unsigned short* msg1F = feat16;   // feat16 dead after layer 0
    (void)ws_size;

    const int gemm_blocks = (N + 127) / 128;

    // --- zero bucketCnt, then fused prep + coarse count ---
    hipMemsetAsync(bucketCnt, 0, 512 * 4, stream);
    prep_count_kernel<<<PREP_BLKS + nblk, 256, 0, stream>>>(
        feat, feat16, feat8, Ws0, Wn0, Ws1, Wn1, wt0, wt1,
        edst, bucketCnt, blockBase, E);

    // --- partitioned CSR build ---
    part_scan_kernel<<<1, 512, 0, stream>>>(bucketCnt, bucketStart, E);
    part_scatter_kernel<<<nblk, 256, 0, stream>>>(esrc, edst, bucketStart, blockBase, pairs, E);
    part_fine_kernel<<<PB, 256, 0, stream>>>(pairs, bucketStart, row_ptr, col, N, E);

    // --- Layer 0 (fused gather + GEMM + LN/ReLU) ---
    sage_layer_kernel<<<gemm_blocks, 256, 0, stream>>>(
        feat16, feat8, row_ptr, col, indeg, wt0, b0, lng, lnb,
        h116, h18, N);

    // --- Layer 1 (gather -> F-layout msg; then GEMM -> fp32 out) ---
    gather8f_kernel<<<gemm_blocks, 256, 0, stream>>>(h18, row_ptr, col, indeg, msg1F, N);
    mfma32_kernel<<<gemm_blocks, 256, 0, stream>>>(h116, msg1F, wt1, b1, out, N);
}

// Round 7
// 313.933 us; speedup vs baseline: 1.2079x; 1.2079x over previous
//
#include <hip/hip_runtime.h>

#define D 128
#define NN 100000
#define PB 391          // coarse buckets: dst >> 8
#define EPB 4096        // edges per partition block
#define PREP_BLKS 12756 // 12500 cvt + 256 wt

typedef __attribute__((ext_vector_type(8))) short short8;
typedef __attribute__((ext_vector_type(16))) float floatx16;
typedef __attribute__((ext_vector_type(2))) float floatx2;

__device__ inline unsigned short bf16_rne(float f) {
    unsigned int u = __float_as_uint(f);
    u += 0x7fff + ((u >> 16) & 1);
    return (unsigned short)(u >> 16);
}
__device__ inline unsigned char fp8_enc1(float f) {
    return (unsigned char)(__builtin_amdgcn_cvt_pk_fp8_f32(f, f, 0, false) & 0xff);
}

// ---------------------------------------------------------------------------
// F-layout (MFMA A-fragment order) for a [N][128] bf16 matrix, N%32==0:
//   F(n,d) = (n>>5)*4096 + ((d>>3)*32 + (n&31))*8 + (d&7)      [elements]
// A-fragment load for 32x32x16 MFMA (lane=hf*32+r, k=kc*16+hf*8+j) is then
//   tile_base + kc*512 + lane*8  -> linear 1KB coalesced wave load.
//
// LESSONS ENCODED:
//  * r5: within one kernel, write regions must be disjoint from all read
//    regions (block order undefined) -> layers stay as separate dispatches.
//  * r6: gather is latency-bound; it needs MANY blocks (TLP), not fusion.
//    128-node blocks (8 serial reps) collapsed concurrency 8x. 32-node
//    blocks (3125 blocks, 2 reps) keep TLP AND allow linear F-store.
// ---------------------------------------------------------------------------

// Fused prep+count: [0,12500) cvt feat->bf16(F-layout)+fp8 | [12500,12756)
// build Wt in B-fragment order | [12756, 12756+nblk) coarse edge count.
__global__ __launch_bounds__(256) void prep_count_kernel(
    const float* __restrict__ feat, unsigned short* __restrict__ feat16,
    unsigned char* __restrict__ feat8,
    const float* __restrict__ Ws0, const float* __restrict__ Wn0,
    const float* __restrict__ Ws1, const float* __restrict__ Wn1,
    unsigned short* __restrict__ wt0, unsigned short* __restrict__ wt1,
    const int* __restrict__ dst, unsigned int* __restrict__ bucketCnt,
    unsigned int* __restrict__ blockBase, int E)
{
    __shared__ unsigned int h[PB];
    int bid = blockIdx.x;
    if (bid < 12500) {
        int i = bid * 256 + threadIdx.x;                 // float4 index
        float4 v = *(const float4*)(feat + (size_t)i * 4);
        unsigned short u[4] = { bf16_rne(v.x), bf16_rne(v.y), bf16_rne(v.z), bf16_rne(v.w) };
        int n  = i >> 5;              // row
        int d0 = (i & 31) * 4;        // col (multiple of 4, within an 8-group)
        size_t f = (size_t)(n >> 5) * 4096 + (size_t)((d0 >> 3) * 32 + (n & 31)) * 8 + (d0 & 7);
        *(uint2*)(feat16 + f) = *(uint2*)u;
        int w = __builtin_amdgcn_cvt_pk_fp8_f32(v.x, v.y, 0, false);
        w = __builtin_amdgcn_cvt_pk_fp8_f32(v.z, v.w, w, true);
        ((unsigned int*)feat8)[i] = (unsigned int)w;     // fp8 stays row-major
    } else if (bid < PREP_BLKS) {
        int i = (bid - 12500) * 256 + threadIdx.x;       // 0..65535
        int layer = i >> 15;
        int r = i & 32767;
        int n = r >> 8;
        int k = r & 255;
        const float* Ws = layer ? Ws1 : Ws0;
        const float* Wn = layer ? Wn1 : Wn0;
        float v = (k < 128) ? Ws[(size_t)k * 128 + n] : Wn[(size_t)(k - 128) * 128 + n];
        unsigned short* wt = layer ? wt1 : wt0;
        // B-fragment order
        int ct = n >> 5, nn = n & 31;
        int hs = k >> 7, k7 = k & 127;
        int kc = k7 >> 4, hf = (k7 >> 3) & 1, j = k7 & 7;
        int frag = ((((ct * 2 + hs) * 8 + kc) * 2 + hf) * 32 + nn) * 8 + j;
        wt[frag] = bf16_rne(v);
    } else {
        const int b = bid - PREP_BLKS;
        const int t = threadIdx.x;
        for (int i = t; i < PB; i += 256) h[i] = 0;
        __syncthreads();
        const int base = b * EPB;
#pragma unroll
        for (int k = 0; k < EPB / 256; k++) {
            int e = base + k * 256 + t;
            if (e < E) atomicAdd(&h[(unsigned)dst[e] >> 8], 1u);
        }
        __syncthreads();
        for (int i = t; i < PB; i += 256) {
            unsigned int c = h[i];
            unsigned int o = 0;
            if (c) o = atomicAdd(&bucketCnt[i], c);
            blockBase[(size_t)b * PB + i] = o;
        }
    }
}

// single block: exclusive scan of PB bucket counts -> bucketStart[PB+1]
__global__ __launch_bounds__(512) void part_scan_kernel(
    const unsigned int* __restrict__ bucketCnt, unsigned int* __restrict__ bucketStart,
    int E)
{
    __shared__ unsigned int sd[512];
    int t = threadIdx.x;
    unsigned int v = (t < PB) ? bucketCnt[t] : 0u;
    sd[t] = v; __syncthreads();
    for (int off = 1; off < 512; off <<= 1) {
        unsigned int x = (t >= off) ? sd[t - off] : 0u;
        __syncthreads();
        sd[t] += x;
        __syncthreads();
    }
    if (t < PB) bucketStart[t] = sd[t] - v;
    if (t == 0) bucketStart[PB] = (unsigned int)E;
}

// P2: scatter packed (src<<8 | dst&255) into bucket regions; ranks via LDS.
__global__ __launch_bounds__(256) void part_scatter_kernel(
    const int* __restrict__ src, const int* __restrict__ dst,
    const unsigned int* __restrict__ bucketStart,
    const unsigned int* __restrict__ blockBase,
    unsigned int* __restrict__ pairs, int E)
{
    __shared__ unsigned int h[PB];
    const int t = threadIdx.x;
    const int b = blockIdx.x;
    for (int i = t; i < PB; i += 256) h[i] = 0;
    __syncthreads();
    const int base = b * EPB;
#pragma unroll
    for (int k = 0; k < EPB / 256; k++) {
        int e = base + k * 256 + t;
        if (e < E) {
            unsigned int d = (unsigned int)dst[e];
            unsigned int bk = d >> 8;
            unsigned int lr = atomicAdd(&h[bk], 1u);
            unsigned int pos = bucketStart[bk] + blockBase[(size_t)b * PB + bk] + lr;
            pairs[pos] = ((unsigned int)src[e] << 8) | (d & 255u);
        }
    }
}

// P3: per-bucket fine CSR (256 dsts): LDS hist + scan -> row_ptr, cursor -> col.
__global__ __launch_bounds__(256) void part_fine_kernel(
    const unsigned int* __restrict__ pairs, const unsigned int* __restrict__ bucketStart,
    int* __restrict__ row_ptr, int* __restrict__ col, int N, int E)
{
    __shared__ unsigned int h[256], sc[256], pos[256];
    const int t = threadIdx.x;
    const int b = blockIdx.x;
    h[t] = 0;
    __syncthreads();
    const unsigned int ebeg = bucketStart[b];
    const unsigned int eend = bucketStart[b + 1];
    for (unsigned int i = ebeg + t; i < eend; i += 256)
        atomicAdd(&h[pairs[i] & 255u], 1u);
    __syncthreads();
    sc[t] = h[t]; __syncthreads();
    for (int off = 1; off < 256; off <<= 1) {
        unsigned int x = (t >= off) ? sc[t - off] : 0u;
        __syncthreads();
        sc[t] += x;
        __syncthreads();
    }
    unsigned int excl = sc[t] - h[t];
    int node = b * 256 + t;
    if (node < N) row_ptr[node] = (int)(ebeg + excl);
    pos[t] = ebeg + excl;
    if (b == 0 && t == 0) row_ptr[N] = E;
    __syncthreads();
    for (unsigned int i = ebeg + t; i < eend; i += 256) {
        unsigned int p = pairs[i];
        unsigned int w = atomicAdd(&pos[p & 255u], 1u);
        col[w] = (int)(p >> 8);
    }
}

// ---------------------------------------------------------------------------
// Gather -> F-layout, 32 nodes/block (3125 blocks => ~48 waves/CU queued):
// per 16-lane group, 2 serial nodes; per node, 16 lanes own 8-elem d-slices.
// Result staged in 8KB LDS (XOR chunk swizzle: ci=ln16*32+lr, sl=ci^((ci>>5)&7)
// -> uniform bank use for quad-writes AND linear reads), then ONE fully
// contiguous 8KB block store in global F-order (fixes r4's 64B-piece scatter
// while keeping r4's gather TLP -- r6 showed 128-node blocks lose 8x TLP).
// ---------------------------------------------------------------------------
__global__ __launch_bounds__(256) void gather32f_kernel(
    const unsigned char* __restrict__ h8, const int* __restrict__ row_ptr,
    const int* __restrict__ col, const int* __restrict__ in_deg,
    unsigned short* __restrict__ msg16, int N)   // msg16: F-layout base
{
    __shared__ char smem[8192];
    const int tid  = threadIdx.x;
    const int nq   = tid >> 4;        // 0..15
    const int ln16 = tid & 15;
    const int brow0 = blockIdx.x * 32;
    const size_t lo = (size_t)ln16 * 8;

#pragma unroll 1
    for (int rep = 0; rep < 2; rep++) {
        int lr = rep * 16 + nq;       // 0..31
        int node = brow0 + lr;
        if (node < N) {
            int beg = row_ptr[node];
            int end = row_ptr[node + 1];
            float f[8] = {0.f,0.f,0.f,0.f,0.f,0.f,0.f,0.f};
            int j = beg;
            for (; j + 4 <= end; j += 4) {
                int c0 = col[j], c1 = col[j + 1], c2 = col[j + 2], c3 = col[j + 3];
                uint2 u0 = *(const uint2*)(h8 + (size_t)c0 * D + lo);
                uint2 u1 = *(const uint2*)(h8 + (size_t)c1 * D + lo);
                uint2 u2 = *(const uint2*)(h8 + (size_t)c2 * D + lo);
                uint2 u3 = *(const uint2*)(h8 + (size_t)c3 * D + lo);
#pragma unroll
                for (int q = 0; q < 4; q++) {
                    uint2 u = q == 0 ? u0 : q == 1 ? u1 : q == 2 ? u2 : u3;
                    floatx2 p0 = __builtin_amdgcn_cvt_pk_f32_fp8((int)u.x, false);
                    floatx2 p1 = __builtin_amdgcn_cvt_pk_f32_fp8((int)u.x, true);
                    floatx2 p2 = __builtin_amdgcn_cvt_pk_f32_fp8((int)u.y, false);
                    floatx2 p3 = __builtin_amdgcn_cvt_pk_f32_fp8((int)u.y, true);
                    f[0] += p0.x; f[1] += p0.y; f[2] += p1.x; f[3] += p1.y;
                    f[4] += p2.x; f[5] += p2.y; f[6] += p3.x; f[7] += p3.y;
                }
            }
            for (; j < end; ++j) {
                uint2 u = *(const uint2*)(h8 + (size_t)col[j] * D + lo);
                floatx2 p0 = __builtin_amdgcn_cvt_pk_f32_fp8((int)u.x, false);
                floatx2 p1 = __builtin_amdgcn_cvt_pk_f32_fp8((int)u.x, true);
                floatx2 p2 = __builtin_amdgcn_cvt_pk_f32_fp8((int)u.y, false);
                floatx2 p3 = __builtin_amdgcn_cvt_pk_f32_fp8((int)u.y, true);
                f[0] += p0.x; f[1] += p0.y; f[2] += p1.x; f[3] += p1.y;
                f[4] += p2.x; f[5] += p2.y; f[6] += p3.x; f[7] += p3.y;
            }
            int dg = in_deg[node];
            float invd = 1.f / (float)(dg > 1 ? dg : 1);
            unsigned short us[8];
#pragma unroll
            for (int i = 0; i < 8; i++) us[i] = bf16_rne(f[i] * invd);
            int ci = (ln16 << 5) + lr;            // chunk in 32-row tile
            int sl = ci ^ ((ci >> 5) & 7);
            *(uint4*)(smem + sl * 16) = *(const uint4*)us;
        }
    }
    __syncthreads();
    // linear copy-out: 512 chunks = 8KB contiguous; LDS de-swizzled
#pragma unroll
    for (int i = 0; i < 2; i++) {
        int ch = tid + i * 256;                   // 0..511
        if (brow0 + (ch & 31) < N) {
            int sl = ch ^ ((ch >> 5) & 7);
            *(uint4*)(msg16 + (size_t)brow0 * D + ch * 8) = *(const uint4*)(smem + sl * 16);
        }
    }
}

// ---------------------------------------------------------------------------
// MFMA dual-GEMM 32x32x16_bf16 (r4-verified): barrier-free K-loop, F-layout
// A/Msg from global (linear 1KB wave loads), B fragment table (L2-hot).
//  * do_ln: LN+ReLU -> bf16(F-layout, LDS-staged linear store) + fp8 row-major.
//  * else : direct fp32 full-128B-line stores, zero barriers.
// C/D: col=lane&31, row=(reg&3)+8*(reg>>2)+4*(lane>>5).
// ---------------------------------------------------------------------------
__global__ __launch_bounds__(256, 3) void mfma32_kernel(
    const unsigned short* __restrict__ A16, const unsigned short* __restrict__ Msg16,
    const unsigned short* __restrict__ Wt,   // B-fragment order, 32768 bf16
    const float* __restrict__ bias,
    const float* __restrict__ ln_g, const float* __restrict__ ln_b,
    unsigned short* __restrict__ Out16, unsigned char* __restrict__ Out8,
    float* __restrict__ Out32, int N, int do_ln)
{
    __shared__ char smem[49152];   // [0,32K): sO16 (F-order), [32K,48K): sO8

    const int tid  = threadIdx.x;
    const int wave = tid >> 6;
    const int lane = tid & 63;
    const int half = lane >> 5;
    const int n32  = lane & 31;
    const int brow0 = blockIdx.x * 128;
    const int wrow0 = brow0 + wave * 32;

    const int NT = N >> 5;
    int tile = wrow0 >> 5;
    if (tile >= NT) tile = NT - 1;           // clamp: stores guarded below
    const short8* Af = (const short8*)(A16   + (size_t)tile * 4096);
    const short8* Mf = (const short8*)(Msg16 + (size_t)tile * 4096);

    floatx16 acc[4];
#pragma unroll
    for (int ct = 0; ct < 4; ct++)
#pragma unroll
        for (int r = 0; r < 16; r++) acc[ct][r] = 0.f;

    // ---- K-loop: all loads linear-coalesced, no LDS, no barriers ----
#pragma unroll
    for (int hs = 0; hs < 2; hs++) {
        const short8* Sf = hs ? Mf : Af;
#pragma unroll
        for (int kc = 0; kc < 8; kc++) {
            short8 a = Sf[kc * 64 + lane];
#pragma unroll
            for (int ct = 0; ct < 4; ct++) {
                short8 b = *(const short8*)(Wt + ((size_t)((ct * 2 + hs) * 8 + kc) * 64 + lane) * 8);
                acc[ct] = __builtin_amdgcn_mfma_f32_32x32x16_bf16(a, b, acc[ct], 0, 0, 0);
            }
        }
    }

    // ---- Epilogue ----
    float bb[4];
#pragma unroll
    for (int ct = 0; ct < 4; ct++) bb[ct] = bias[ct * 32 + n32];

    float v[4][16];
#pragma unroll
    for (int ct = 0; ct < 4; ct++)
#pragma unroll
        for (int r = 0; r < 16; r++) v[ct][r] = acc[ct][r] + bb[ct];

    if (do_ln) {
        float gg[4], be[4];
#pragma unroll
        for (int ct = 0; ct < 4; ct++) {
            gg[ct] = ln_g[ct * 32 + n32];
            be[ct] = ln_b[ct * 32 + n32];
        }
        float s[16], s2[16];
#pragma unroll
        for (int r = 0; r < 16; r++) {
            s[r]  = v[0][r] + v[1][r] + v[2][r] + v[3][r];
            s2[r] = v[0][r]*v[0][r] + v[1][r]*v[1][r] + v[2][r]*v[2][r] + v[3][r]*v[3][r];
        }
#pragma unroll
        for (int off = 1; off < 32; off <<= 1) {
#pragma unroll
            for (int r = 0; r < 16; r++) {
                s[r]  += __shfl_xor(s[r],  off);
                s2[r] += __shfl_xor(s2[r], off);
            }
        }
        unsigned char* sO8 = (unsigned char*)smem + 32768;       // [128][128] byte
#pragma unroll
        for (int r = 0; r < 16; r++) {
            float mean = s[r] * (1.f / 128.f);
            float var  = s2[r] * (1.f / 128.f) - mean * mean;
            float rstd = rsqrtf(var + 1e-5f);
            int brow = wave * 32 + (r & 3) + 8 * (r >> 2) + 4 * half;
#pragma unroll
            for (int ct = 0; ct < 4; ct++) {
                float t = (v[ct][r] - mean) * rstd * gg[ct] + be[ct];
                t = t > 0.f ? t : 0.f;
                // sO16 in F-order with XOR slot swizzle (conflict-free 2B writes)
                int slot = (ct * 4 + (n32 >> 3)) ^ (brow & 15);
                *(unsigned short*)(smem + brow * 256 + slot * 16 + (n32 & 7) * 2) = bf16_rne(t);
                sO8[brow * 128 + ct * 32 + n32] = fp8_enc1(t);
            }
        }
        __syncthreads();
        // Out16 (F-layout): linear global writes; LDS reads de-swizzled
#pragma unroll
        for (int i = 0; i < 8; i++) {                 // 2048 uint4 chunks
            int ch = tid + i * 256;
            int tl = ch >> 9, p = ch & 511, kc2 = p >> 5, rr = p & 31;
            if (brow0 + tl * 32 + rr < N)
                *(uint4*)(Out16 + (size_t)brow0 * D + ch * 8) =
                    *(const uint4*)&smem[(tl * 32 + rr) * 256 + ((kc2 ^ (rr & 15)) * 16)];
        }
#pragma unroll
        for (int i = 0; i < 4; i++) {                 // fp8: 1024 uint4 chunks
            int ch = tid + i * 256;
            if (brow0 + (ch >> 3) < N)
                *(uint4*)(Out8 + (size_t)brow0 * D + ch * 16) = *(const uint4*)&sO8[ch * 16];
        }
    } else {
        // direct fp32 stores: 32 lanes x 4B consecutive = full 128B line
#pragma unroll
        for (int r = 0; r < 16; r++) {
            int row = wrow0 + (r & 3) + 8 * (r >> 2) + 4 * half;
            if (row < N) {
#pragma unroll
                for (int ct = 0; ct < 4; ct++)
                    Out32[(size_t)row * D + ct * 32 + n32] = v[ct][r];
            }
        }
    }
}

// ---------------------------------------------------------------------------
extern "C" void kernel_launch(void* const* d_in, const int* in_sizes, int n_in,
                              void* d_out, int out_size, void* d_ws, size_t ws_size,
                              hipStream_t stream)
{
    const float* feat = (const float*)d_in[0];
    const float* Ws0  = (const float*)d_in[1];
    const float* Wn0  = (const float*)d_in[2];
    const float* b0   = (const float*)d_in[3];
    const float* Ws1  = (const float*)d_in[4];
    const float* Wn1  = (const float*)d_in[5];
    const float* b1   = (const float*)d_in[6];
    const float* lng  = (const float*)d_in[7];
    const float* lnb  = (const float*)d_in[8];
    const int* esrc   = (const int*)d_in[9];
    const int* edst   = (const int*)d_in[10];
    const int* indeg  = (const int*)d_in[11];

    const int N = NN;
    const int E = in_sizes[9];

    float* out = (float*)d_out;

    // ws: feat16 | col | row_ptr | wt0 | wt1 | regD
    //   regD overlay (CSR build): bucketCnt | bucketStart | blockBase | pairs
    //   regD overlay (compute):   h1_16
    // d_out overlay (dead until final dispatch):
    //   [0,25.6M): msg0 | [25.6M,38.4M): feat8 | [38.4M,51.2M): h18
    // Dispatch-level safety (each line: reads -> writes, all disjoint):
    //   g32f L0:  feat8, CSR           -> msg0
    //   mfma L0:  feat16, msg0, wt0    -> h116(ws), h18
    //   g32f L1:  h18, CSR             -> msg1F (=feat16 region, dead)
    //   mfma L1:  h116, msg1F, wt1     -> out (msg0/feat8/h18 all dead)
    const int nblk = (E + EPB - 1) / EPB;
    char* ws = (char*)d_ws;
    size_t o = 0;
    auto alloc = [&](size_t bytes) { char* p = ws + o; o += (bytes + 15) & ~(size_t)15; return p; };
    unsigned short* feat16 = (unsigned short*)alloc((size_t)N * D * 2);
    int* col     = (int*)alloc((size_t)E * 4);
    int* row_ptr = (int*)alloc((size_t)(N + 1) * 4);
    unsigned short* wt0 = (unsigned short*)alloc(128 * 256 * 2);
    unsigned short* wt1 = (unsigned short*)alloc(128 * 256 * 2);
    size_t csr_bytes = (size_t)(512 + 512 + (size_t)nblk * PB + E) * 4 + 64;
    char* regD = alloc((size_t)N * D * 2 > csr_bytes ? (size_t)N * D * 2 : csr_bytes);
    unsigned int* bucketCnt   = (unsigned int*)regD;                  // 512 slots
    unsigned int* bucketStart = bucketCnt + 512;                      // 512 slots
    unsigned int* blockBase   = bucketStart + 512;                    // nblk*PB
    unsigned int* pairs       = blockBase + (size_t)nblk * PB;        // E
    unsigned short* h116 = (unsigned short*)regD;

    unsigned short* msg0  = (unsigned short*)d_out;
    unsigned char*  feat8 = (unsigned char*)d_out + (size_t)N * D * 2;
    unsigned char*  h18   = (unsigned char*)d_out + (size_t)N * D * 3;
    unsigned short* msg1F = feat16;   // feat16 dead after layer 0
    (void)ws_size;

    const int gemm_blocks = (N + 127) / 128;
    const int g32_blocks  = (N + 31) / 32;      // 3125, N%32==0

    // --- zero bucketCnt, then fused prep + coarse count ---
    hipMemsetAsync(bucketCnt, 0, 512 * 4, stream);
    prep_count_kernel<<<PREP_BLKS + nblk, 256, 0, stream>>>(
        feat, feat16, feat8, Ws0, Wn0, Ws1, Wn1, wt0, wt1,
        edst, bucketCnt, blockBase, E);

    // --- partitioned CSR build ---
    part_scan_kernel<<<1, 512, 0, stream>>>(bucketCnt, bucketStart, E);
    part_scatter_kernel<<<nblk, 256, 0, stream>>>(esrc, edst, bucketStart, blockBase, pairs, E);
    part_fine_kernel<<<PB, 256, 0, stream>>>(pairs, bucketStart, row_ptr, col, N, E);

    // --- Layer 0 ---
    gather32f_kernel<<<g32_blocks, 256, 0, stream>>>(feat8, row_ptr, col, indeg, msg0, N);
    mfma32_kernel<<<gemm_blocks, 256, 0, stream>>>(
        feat16, msg0, wt0, b0, lng, lnb, h116, h18, nullptr, N, 1);

    // --- Layer 1 ---
    gather32f_kernel<<<g32_blocks, 256, 0, stream>>>(h18, row_ptr, col, indeg, msg1F, N);
    mfma32_kernel<<<gemm_blocks, 256, 0, stream>>>(
        h116, msg1F, wt1, b1, nullptr, nullptr, nullptr, nullptr, out, N, 0);
}